// Round 18
// baseline (797.120 us; speedup 1.0000x reference)
//
#include <hip/hip_runtime.h>
#include <math.h>

// Model dims (fixed by the reference)
#define T_DIM 512
#define B_DIM 64
#define J_DIM 256
#define H_DIM 256
#define K_TAP 25
#define NL    3
#define M_DIM (T_DIM*B_DIM)   // 32768 rows = (t,b)
#define NBH   (B_DIM*H_DIM)   // 16384
#define GUARD_ROWS 1536                  // 64*24 zero rows before row 0
#define GUARD_BYTES (GUARD_ROWS*J_DIM)   // 393216

// conv GEMM tiling: 128(M) x 64(N) block, 4 waves (2x2), wave tile 64x32.
// PERIOD = 128 K-elems (2 MFMA sub-steps of 64). 50 periods.
#define MB 128
#define NB 64
#define NPER 50
#define SETB 24576   // per LDS set (B only): B0 @0 | B1 @8192 | B2 @16384

typedef __attribute__((ext_vector_type(4))) int   i32x4;

__device__ __forceinline__ void gl16(const void* g, void* l){ // async global->LDS, 16B/lane
  __builtin_amdgcn_global_load_lds((const __attribute__((address_space(1))) unsigned int*)g,
                                   (__attribute__((address_space(3))) unsigned int*)l, 16, 0, 0);
}

// ---------------------------------------------------------------------------
// 0a) zero guard region + BN integer-accumulator region (ws is poisoned)
// ---------------------------------------------------------------------------
__global__ void zero_guard_k(unsigned char* __restrict__ g, unsigned char* __restrict__ p){
  const int bid = blockIdx.x;
  if(bid < 96) *(uint4*)(g + (size_t)(bid*256 + threadIdx.x)*16) = (uint4){0,0,0,0};
  else         *(uint4*)(p + (size_t)((bid-96)*256 + threadIdx.x)*16) = (uint4){0,0,0,0};
}

// 0b) cast f32 binary input -> u8 spikes
__global__ void cast_u8_k(const float* __restrict__ x, unsigned char* __restrict__ s){
  const int i = blockIdx.x*256 + threadIdx.x;       // one float4 per thread
  const float4 v = *(const float4*)(x + (size_t)i*4);
  uchar4 o; o.x=(unsigned char)v.x; o.y=(unsigned char)v.y;
  o.z=(unsigned char)v.z; o.w=(unsigned char)v.w;
  *(uchar4*)(s + (size_t)i*4) = o;
}

// ---------------------------------------------------------------------------
// 1) DCLS gaussian kernel -> 23-bit fixed point, 3 signed-i8 digit planes.
//    kd[d][o][j] = W[o,j]*gnorm[o,j,k=24-d].  Per-column power-of-2 scale s_o;
//    q = rint(kd/s_o * 2^22); q = b2*2^16 + b1*2^8 + b0 exactly.
//    fsc[o] = s_o * 2^-22 (exact power of 2).
// ---------------------------------------------------------------------------
__global__ void build_kern_k(const float* __restrict__ W, const float* __restrict__ P,
                             signed char* __restrict__ k0, signed char* __restrict__ k1,
                             signed char* __restrict__ k2, float* __restrict__ fsc, int layer){
  __shared__ float red[256];
  const int o = blockIdx.x, j = threadIdx.x;
  const float w = W[(layer*H_DIM + o)*J_DIM + j];
  const float p = P[(layer*H_DIM + o)*J_DIM + j];
  const float c = p + 12.0f;              // P + K//2
  const float sg = 0.77f;                 // |0.5| + 0.27
  float v[K_TAP]; float ssum = 0.f;
#pragma unroll
  for(int k=0;k<K_TAP;k++){ float z = ((float)k - c)/sg; v[k] = expf(-0.5f*z*z); ssum += v[k]; }
  const float inv = 1.0f/(ssum + 1e-7f);
  float mv = 0.f;
#pragma unroll
  for(int k=0;k<K_TAP;k++){ v[k] = w * (v[k]*inv); mv = fmaxf(mv, fabsf(v[k])); }
  red[j] = mv; __syncthreads();
  for(int st=128; st; st>>=1){ if(j<st) red[j] = fmaxf(red[j], red[j+st]); __syncthreads(); }
  int e; frexpf(red[0], &e);              // maxv = f*2^e, f in [0.5,1)
  const float invq = ldexpf(1.f, 22 - e); // 2^22 / s_o
#pragma unroll
  for(int k=0;k<K_TAP;k++){
    const int d = (K_TAP-1)-k;
    int q = (int)lrintf(v[k]*invq);
    const int b0 = (int)(signed char)(q & 0xFF); q = (q - b0) >> 8;
    const int b1 = (int)(signed char)(q & 0xFF); q = (q - b1) >> 8;
    const size_t idx = (size_t)(d*H_DIM + o)*J_DIM + j;
    k0[idx] = (signed char)b0; k1[idx] = (signed char)b1; k2[idx] = (signed char)q;
  }
  if(j==0) fsc[o] = ldexpf(1.f, e - 22);
}

// ---------------------------------------------------------------------------
// 2) Delayed causal conv as EXACT i8 MFMA GEMM (3 digit planes, i32 acc).
//    128x64 block, 4 waves 2x2, wave tile 64x32, mfma_i32_16x16x64_i8.
//    r17 period structure (128 K-elems, ONE {vmcnt(0);barrier} per period)
//    with A moved OUT of LDS: A fragments load DIRECTLY global->register
//    (8 plain i32x4 loads/period/wave, compiler-tracked) with PERIOD-deep
//    prefetch into named ping-pong arrays afA/afB (loop unrolled x2, rule
//    #20). The loads issue during period p and are consumed in p+1 after
//    the entry vmcnt(0) -- a full ~3000-cyc latency cover (this fixes
//    r11/13's per-substep A-direct latency exposure). LDS is B-only:
//    2 x 24KB double-buffered sets -> per period per wave the LDS pipe
//    drops from 20 reads + 10 gl16 to 12 reads + 6 gl16 (the r17 wall).
//    Race proof (unchanged r17/r14 pattern): B set (p+1)&1 staged during p
//    was last read in period p-1; those ds_reads retire before each wave's
//    barrier(p) arrival; stage writes issue only after barrier(p). Reads
//    of set p&1 follow each wave's own vmcnt(0)+barrier -> visible.
//    128B rows, 8-slot XOR swizzle (phys16Bslot = logical ^ (row&7)); gl16
//    stays linear with SOURCE col pre-permuted (rule 21 both-sides).
//    XCD n0-major (T1); fused exact-integer BN epilogue.
// ---------------------------------------------------------------------------
__global__ __launch_bounds__(256,2) void conv_mfma_k(const unsigned char* __restrict__ spk,
    const signed char* __restrict__ k0, const signed char* __restrict__ k1,
    const signed char* __restrict__ k2, const float* __restrict__ fsc,
    float* __restrict__ y, long long* __restrict__ part){
  __shared__ unsigned char lds[2][SETB];
  const int tid = threadIdx.x, lane = tid & 63, wave = tid >> 6;
  // XCD-aware n0-major decode: xcd = bid%8 owns 128 consecutive q's
  const int bid = blockIdx.x;                      // 0..1023
  const int q   = (bid & 7)*128 + (bid >> 3);
  const int m0  = (q & 255) * MB;
  const int n0  = (q >> 8) * NB;
  const int wm0 = (wave >> 1) << 6;   // 0 / 64
  const int wn0 = (wave & 1) << 5;    // 0 / 32

  // B staging map: thread t -> row 32i + (t>>3), phys 16B slot t&7;
  // source col pre-permuted: lcol = ((t&7) ^ ((t>>3)&7)) * 16
  const int srow32 = tid >> 3;                       // 0..31
  const int lcol   = (((tid & 7) ^ (srow32 & 7)) << 4);
  const int wv1k   = wave * 1024;
  const int l15 = lane & 15, l7 = lane & 7, lg = lane >> 4;

  // A fragment global base: row = m0+wm0+l15+16m (-64d), 16B k-chunk = lg
  const unsigned char* abase = spk + (size_t)(m0 + wm0 + l15 + GUARD_ROWS)*J_DIM + (lg<<4);

  i32x4 acc0[4][2], acc1[4][2], acc2[4][2];
#pragma unroll
  for(int m=0;m<4;m++)
#pragma unroll
    for(int n=0;n<2;n++){
      acc0[m][n] = (i32x4){0,0,0,0};
      acc1[m][n] = (i32x4){0,0,0,0};
      acc2[m][n] = (i32x4){0,0,0,0};
    }

  i32x4 afA[8], afB[8];   // [s*4+m], ping-pong across periods

#define STAGE_B(sb,p) do{ \
    const int d_ = (p)>>1, jc_ = ((p)&1)<<7; \
    unsigned char* lb_ = &lds[(sb)][0]; \
    const size_t bo_ = (size_t)(d_*H_DIM + n0 + srow32)*J_DIM + jc_ + lcol; \
    gl16(k0 + bo_,                    lb_         + wv1k); \
    gl16(k0 + bo_ + (size_t)32*J_DIM, lb_ + 4096  + wv1k); \
    gl16(k1 + bo_,                    lb_ + 8192  + wv1k); \
    gl16(k1 + bo_ + (size_t)32*J_DIM, lb_ + 12288 + wv1k); \
    gl16(k2 + bo_,                    lb_ + 16384 + wv1k); \
    gl16(k2 + bo_ + (size_t)32*J_DIM, lb_ + 20480 + wv1k); \
  }while(0)

#define LOAD_AF(AF,p) do{ \
    const int d_ = (p)>>1, jc_ = ((p)&1)<<7; \
    const unsigned char* a0_ = abase - (size_t)(d_<<6)*J_DIM + jc_; \
    AF[0] = *(const i32x4*)(a0_);              \
    AF[1] = *(const i32x4*)(a0_ + 4096);       \
    AF[2] = *(const i32x4*)(a0_ + 8192);       \
    AF[3] = *(const i32x4*)(a0_ + 12288);      \
    AF[4] = *(const i32x4*)(a0_ + 64);         \
    AF[5] = *(const i32x4*)(a0_ + 4096 + 64);  \
    AF[6] = *(const i32x4*)(a0_ + 8192 + 64);  \
    AF[7] = *(const i32x4*)(a0_ + 12288 + 64); \
  }while(0)

#define PERIOD(p, AFU, AFL) do{ \
    asm volatile("s_waitcnt vmcnt(0)" ::: "memory");   /* B(p)+AF(p) landed */ \
    __builtin_amdgcn_s_barrier();                      /* all waves' B(p) visible */ \
    __builtin_amdgcn_sched_barrier(0); \
    if((p)+1 < NPER){ STAGE_B(((p)+1)&1, (p)+1); LOAD_AF(AFL, (p)+1); } \
    const unsigned char* S_ = &lds[(p)&1][0]; \
    _Pragma("unroll") \
    for(int s=0;s<2;s++){ \
      const int rs_ = (((lg + (s<<2)) ^ l7) << 4); \
      i32x4 b0f[2], b1f[2], b2f[2]; \
      _Pragma("unroll") \
      for(int n=0;n<2;n++){ \
        const int ro_ = (wn0 + n*16 + l15)*128 + rs_; \
        b0f[n] = *(const i32x4*)(S_ + ro_); \
        b1f[n] = *(const i32x4*)(S_ + 8192  + ro_); \
        b2f[n] = *(const i32x4*)(S_ + 16384 + ro_); \
      } \
      __builtin_amdgcn_s_setprio(1); \
      _Pragma("unroll") \
      for(int m=0;m<4;m++) \
      _Pragma("unroll") \
        for(int n=0;n<2;n++){ \
          acc0[m][n] = __builtin_amdgcn_mfma_i32_16x16x64_i8(AFU[s*4+m], b0f[n], acc0[m][n], 0,0,0); \
          acc1[m][n] = __builtin_amdgcn_mfma_i32_16x16x64_i8(AFU[s*4+m], b1f[n], acc1[m][n], 0,0,0); \
          acc2[m][n] = __builtin_amdgcn_mfma_i32_16x16x64_i8(AFU[s*4+m], b2f[n], acc2[m][n], 0,0,0); \
        } \
      __builtin_amdgcn_s_setprio(0); \
    } \
  }while(0)

  // prologue: stage/load period 0
  STAGE_B(0, 0);
  LOAD_AF(afA, 0);

  for(int p=0; p<NPER; p+=2){
    PERIOD(p,   afA, afB);
    PERIOD(p+1, afB, afA);
  }

  // epilogue: C/D mapping col=lane&15, row=(lane>>4)*4+r [shape-determined].
  // Exact int64 digit recombine; y-write; exact integer BN accumulation.
  const int r0 = m0 + wm0 + ((lane>>4)<<2);
  const int c0 = n0 + wn0 + (lane&15);
  const double f0 = (double)fsc[c0];
  const double f1 = (double)fsc[c0+16];
#pragma unroll
  for(int n=0;n<2;n++){
    const double fs = n ? f1 : f0;
    long long s1 = 0; unsigned long long shi = 0, slo = 0;
#pragma unroll
    for(int m=0;m<4;m++)
#pragma unroll
      for(int r=0;r<4;r++){
        const long long cmb = ((long long)acc2[m][n][r] << 16)
                            + ((long long)acc1[m][n][r] << 8)
                            +  (long long)acc0[m][n][r];
        y[(size_t)(r0 + m*16 + r)*H_DIM + c0 + n*16] = (float)((double)cmb * fs);
        s1 += cmb;
        const __int128 sq = (__int128)cmb * cmb;       // >= 0, < 2^70
        slo += (unsigned long long)(unsigned int)sq;   // low 32 bits
        shi += (unsigned long long)(sq >> 32);         // high bits (< 2^38)
      }
    s1  += __shfl_xor(s1, 16);  s1  += __shfl_xor(s1, 32);
    shi += __shfl_xor(shi, 16); shi += __shfl_xor(shi, 32);
    slo += __shfl_xor(slo, 16); slo += __shfl_xor(slo, 32);
    if(lane < 16){
      const int c = c0 + n*16;
      atomicAdd((unsigned long long*)&part[c],       (unsigned long long)s1);
      atomicAdd((unsigned long long*)&part[256 + c], shi);
      atomicAdd((unsigned long long*)&part[512 + c], slo);
    }
  }
#undef STAGE_B
#undef LOAD_AF
#undef PERIOD
}

// ---------------------------------------------------------------------------
// 3) BN finalize from exact integer sums; re-zeros part for the next layer.
//    sum(y) = fs*s1 ; sum(y^2) = fs^2*(shi*2^32+slo) -- fs is a power of 2.
// ---------------------------------------------------------------------------
__global__ void bn_final_k(long long* __restrict__ part, const float* __restrict__ fsc,
                           float* __restrict__ sc, float* __restrict__ sh,
                           const float* __restrict__ gamma_, const float* __restrict__ bb_,
                           int layer){
  const int o = threadIdx.x;
  const long long s1           = part[o];
  const unsigned long long shi = (unsigned long long)part[256 + o];
  const unsigned long long slo = (unsigned long long)part[512 + o];
  part[o] = 0; part[256 + o] = 0; part[512 + o] = 0;   // ready for next layer
  const double fs  = (double)fsc[o];
  const double sy  = (double)s1 * fs;
  const double sy2 = ((double)shi * 4294967296.0 + (double)slo) * fs * fs;
  const double inv_n = 1.0 / (double)M_DIM;
  const double m   = sy * inv_n;
  const double var = sy2 * inv_n - m*m;      // biased, like jnp.var
  const double rs  = 1.0 / sqrt(var + (double)1e-5f);
  const float g  = gamma_[layer*H_DIM + o];
  const float bv = bb_[layer*H_DIM + o];
  const float scale = (float)((double)g * rs);
  sc[o] = scale;
  sh[o] = (float)((double)bv - m*(double)scale);
}

// ---------------------------------------------------------------------------
// 4) LIF soft-reset scan. One thread per (b,h), 16-deep prefetch.
//    TOUT=u8 inter-layer spikes, f32 final output (in-place on d_out).
//    NOTE: no __restrict__ on yin/sout — they alias for the final layer.
// ---------------------------------------------------------------------------
template<typename TOUT>
__global__ void lif_k(const float* yin, TOUT* sout,
                      const float* __restrict__ sc_, const float* __restrict__ sh_,
                      const float* __restrict__ beta_, const float* __restrict__ U0_,
                      int layer){
  const int idx = blockIdx.x*64 + threadIdx.x;   // 0..16383 = b*256+h
  const int h = idx & (H_DIM-1);
  const float scale = sc_[h];
  const float shift = sh_[h];
  const float beta  = beta_[layer*H_DIM + h];
  const float ombeta = 1.0f - beta;
  float U = U0_[layer*NBH + idx];
  float S = 0.f;
  float cur[16];
#pragma unroll
  for(int i=0;i<16;i++) cur[i] = yin[(size_t)i*NBH + idx];
  for(int t=0;t<T_DIM;t+=16){
    float nx[16];
#pragma unroll
    for(int i=0;i<16;i++){
      const int tt = t + 16 + i;
      nx[i] = (tt < T_DIM) ? yin[(size_t)tt*NBH + idx] : 0.f;
    }
#pragma unroll
    for(int i=0;i<16;i++){
      const float yv = fmaf(cur[i], scale, shift);
      U = beta*(U - S) + ombeta*yv;
      S = (U > 1.0f) ? 1.f : 0.f;              // (U - THETA) > 0
      sout[(size_t)(t+i)*NBH + idx] = (TOUT)S;
    }
#pragma unroll
    for(int i=0;i<16;i++) cur[i] = nx[i];
  }
}

// ---------------------------------------------------------------------------
// Launch. ws layout (13.7 MB):
//   spk  [0,          8,781,824)    guard(393216 zeros) + 32768*256 u8 spikes
//   k0   [8,781,824, 10,420,224)    25*256*256 i8 digit 0 (2^0)
//   k1   [10,420,224,12,058,624)    25*256*256 i8 digit 1 (2^8)
//   k2   [12,058,624,13,697,024)    25*256*256 i8 digit 2 (2^16)
//   fsc  [13,697,024,+1024)         256 f32 per-column scale
//   part [13,698,048,+8192)         3*256 i64 BN integer sums (+pad), zeroed
//   sc   [13,706,240,+1024) f32 ; sh [13,707,264,+1024) f32
// Conv y always lands in d_out (fully rewritten each layer before any read).
// ---------------------------------------------------------------------------
extern "C" void kernel_launch(void* const* d_in, const int* in_sizes, int n_in,
                              void* d_out, int out_size, void* d_ws, size_t ws_size,
                              hipStream_t stream){
  const float* x    = (const float*)d_in[0];
  const float* W    = (const float*)d_in[1];
  const float* P    = (const float*)d_in[2];
  const float* beta = (const float*)d_in[3];
  const float* gam  = (const float*)d_in[4];
  const float* bb   = (const float*)d_in[5];
  const float* U0   = (const float*)d_in[6];
  float* out = (float*)d_out;

  char* ws = (char*)d_ws;
  unsigned char* spk  = (unsigned char*)ws;                 // guarded base
  unsigned char* spkd = spk + GUARD_BYTES;                  // data region
  signed char*   k0   = (signed char*)(ws + 8781824);
  signed char*   k1   = (signed char*)(ws + 10420224);
  signed char*   k2   = (signed char*)(ws + 12058624);
  float*         fsc  = (float*)(ws + 13697024);
  long long*     part = (long long*)(ws + 13698048);
  float*         sc   = (float*)(ws + 13706240);
  float*         sh   = sc + 256;

  zero_guard_k<<<dim3(98), dim3(256), 0, stream>>>(spk, (unsigned char*)part);
  cast_u8_k<<<dim3((M_DIM*J_DIM)/1024), dim3(256), 0, stream>>>(x, spkd);

  for(int l=0;l<NL;l++){
    build_kern_k<<<dim3(H_DIM), dim3(J_DIM), 0, stream>>>(W, P, k0, k1, k2, fsc, l);
    conv_mfma_k<<<dim3((M_DIM/MB)*(H_DIM/NB)), dim3(256), 0, stream>>>(spk, k0, k1, k2, fsc, out, part);
    bn_final_k<<<dim3(1), dim3(H_DIM), 0, stream>>>(part, fsc, sc, sh, gam, bb, l);
    if(l < NL-1) lif_k<unsigned char><<<dim3(NBH/64), dim3(64), 0, stream>>>(out, spkd, sc, sh, beta, U0, l);
    else         lif_k<float>        <<<dim3(NBH/64), dim3(64), 0, stream>>>(out, out, sc, sh, beta, U0, l);
  }
}

// Round 19
// 554.581 us; speedup vs baseline: 1.4373x; 1.4373x over previous
//
#include <hip/hip_runtime.h>
#include <math.h>

// Model dims (fixed by the reference)
#define T_DIM 512
#define B_DIM 64
#define J_DIM 256
#define H_DIM 256
#define K_TAP 25
#define NL    3
#define M_DIM (T_DIM*B_DIM)   // 32768 rows = (t,b)
#define NBH   (B_DIM*H_DIM)   // 16384
#define GUARD_ROWS 1536                  // 64*24 zero rows before row 0
#define GUARD_BYTES (GUARD_ROWS*J_DIM)   // 393216

// conv GEMM tiling: 128(M) x 64(N) block, 4 waves (2x2), wave tile 64x32.
// PERIOD = 128 K-elems (2 substeps of 64; each = 2 MFMA-K of 32). 50 periods.
#define MB 128
#define NB 64
#define NPER 50
#define SETB 40960   // per LDS set: A[128][128] @0 | B0 @16384 | B1 @24576 | B2 @32768

typedef __attribute__((ext_vector_type(4)))  int i32x4;
typedef __attribute__((ext_vector_type(16))) int i32x16;

__device__ __forceinline__ void gl16(const void* g, void* l){ // async global->LDS, 16B/lane
  __builtin_amdgcn_global_load_lds((const __attribute__((address_space(1))) unsigned int*)g,
                                   (__attribute__((address_space(3))) unsigned int*)l, 16, 0, 0);
}

// ---------------------------------------------------------------------------
// 0a) zero guard region + BN integer-accumulator region (ws is poisoned)
// ---------------------------------------------------------------------------
__global__ void zero_guard_k(unsigned char* __restrict__ g, unsigned char* __restrict__ p){
  const int bid = blockIdx.x;
  if(bid < 96) *(uint4*)(g + (size_t)(bid*256 + threadIdx.x)*16) = (uint4){0,0,0,0};
  else         *(uint4*)(p + (size_t)((bid-96)*256 + threadIdx.x)*16) = (uint4){0,0,0,0};
}

// 0b) cast f32 binary input -> u8 spikes
__global__ void cast_u8_k(const float* __restrict__ x, unsigned char* __restrict__ s){
  const int i = blockIdx.x*256 + threadIdx.x;       // one float4 per thread
  const float4 v = *(const float4*)(x + (size_t)i*4);
  uchar4 o; o.x=(unsigned char)v.x; o.y=(unsigned char)v.y;
  o.z=(unsigned char)v.z; o.w=(unsigned char)v.w;
  *(uchar4*)(s + (size_t)i*4) = o;
}

// ---------------------------------------------------------------------------
// 1) DCLS gaussian kernel -> 23-bit fixed point, 3 signed-i8 digit planes.
//    kd[d][o][j] = W[o,j]*gnorm[o,j,k=24-d].  Per-column power-of-2 scale s_o;
//    q = rint(kd/s_o * 2^22); q = b2*2^16 + b1*2^8 + b0 exactly.
//    fsc[o] = s_o * 2^-22 (exact power of 2).
// ---------------------------------------------------------------------------
__global__ void build_kern_k(const float* __restrict__ W, const float* __restrict__ P,
                             signed char* __restrict__ k0, signed char* __restrict__ k1,
                             signed char* __restrict__ k2, float* __restrict__ fsc, int layer){
  __shared__ float red[256];
  const int o = blockIdx.x, j = threadIdx.x;
  const float w = W[(layer*H_DIM + o)*J_DIM + j];
  const float p = P[(layer*H_DIM + o)*J_DIM + j];
  const float c = p + 12.0f;              // P + K//2
  const float sg = 0.77f;                 // |0.5| + 0.27
  float v[K_TAP]; float ssum = 0.f;
#pragma unroll
  for(int k=0;k<K_TAP;k++){ float z = ((float)k - c)/sg; v[k] = expf(-0.5f*z*z); ssum += v[k]; }
  const float inv = 1.0f/(ssum + 1e-7f);
  float mv = 0.f;
#pragma unroll
  for(int k=0;k<K_TAP;k++){ v[k] = w * (v[k]*inv); mv = fmaxf(mv, fabsf(v[k])); }
  red[j] = mv; __syncthreads();
  for(int st=128; st; st>>=1){ if(j<st) red[j] = fmaxf(red[j], red[j+st]); __syncthreads(); }
  int e; frexpf(red[0], &e);              // maxv = f*2^e, f in [0.5,1)
  const float invq = ldexpf(1.f, 22 - e); // 2^22 / s_o
#pragma unroll
  for(int k=0;k<K_TAP;k++){
    const int d = (K_TAP-1)-k;
    int q = (int)lrintf(v[k]*invq);
    const int b0 = (int)(signed char)(q & 0xFF); q = (q - b0) >> 8;
    const int b1 = (int)(signed char)(q & 0xFF); q = (q - b1) >> 8;
    const size_t idx = (size_t)(d*H_DIM + o)*J_DIM + j;
    k0[idx] = (signed char)b0; k1[idx] = (signed char)b1; k2[idx] = (signed char)q;
  }
  if(j==0) fsc[o] = ldexpf(1.f, e - 22);
}

// ---------------------------------------------------------------------------
// 2) Delayed causal conv as EXACT i8 MFMA GEMM (3 digit planes, i32 acc).
//    r17 chassis (period=128 K-elems, ONE {vmcnt(0);barrier} per period,
//    2x40KB double-buffered LDS sets, all staging via gl16 -> no
//    compiler/asm vmcnt interference [r18 lesson], 8-slot XOR swizzle with
//    pre-permuted source cols, XCD n0-major) with the MFMA upgraded to
//    mfma_i32_32x32x32_i8: wave tile 64x32 = 2 m-tiles x 1 n-tile of
//    32x32; per 64-K substep: 2 k-chunks x {2 A reads + 3 B reads, 6
//    MFMAs}. Same LDS traffic as 16x16x64, 12% faster i8 pipe, half the
//    issue slots. A/B staged with the SAME (lane-half,byte)->k convention
//    (positional pairing makes the dot product invariant to any common
//    intra-fragment k-permutation; same argument as the verified 16x16x64
//    path). C/D map [m74/m101-verified]: col=lane&31,
//    row=(reg&3)+8*(reg>>2)+4*(lane>>5).
//    Fused exact-integer BN epilogue (order-independent, deterministic).
// ---------------------------------------------------------------------------
__global__ __launch_bounds__(256,2) void conv_mfma_k(const unsigned char* __restrict__ spk,
    const signed char* __restrict__ k0, const signed char* __restrict__ k1,
    const signed char* __restrict__ k2, const float* __restrict__ fsc,
    float* __restrict__ y, long long* __restrict__ part){
  __shared__ unsigned char lds[2][SETB];
  const int tid = threadIdx.x, lane = tid & 63, wave = tid >> 6;
  // XCD-aware n0-major decode: xcd = bid%8 owns 128 consecutive q's
  const int bid = blockIdx.x;                      // 0..1023
  const int q   = (bid & 7)*128 + (bid >> 3);
  const int m0  = (q & 255) * MB;
  const int n0  = (q >> 8) * NB;
  const int wm0 = (wave >> 1) << 6;   // 0 / 64
  const int wn0 = (wave & 1) << 5;    // 0 / 32

  // staging map: thread t -> row 32i + (t>>3), phys 16B slot t&7;
  // source col pre-permuted: lcol = ((t&7) ^ ((t>>3)&7)) * 16
  const int srow32 = tid >> 3;                       // 0..31
  const int lcol   = (((tid & 7) ^ (srow32 & 7)) << 4);
  const int wv1k   = wave * 1024;
  const int l31 = lane & 31, l7 = lane & 7, hlf = lane >> 5;

  i32x16 acc0[2], acc1[2], acc2[2];
#pragma unroll
  for(int mt=0;mt<2;mt++){
#pragma unroll
    for(int r=0;r<16;r++){ acc0[mt][r]=0; acc1[mt][r]=0; acc2[mt][r]=0; }
  }

#define STAGE(sbase,p) do{ \
    const int d_ = (p)>>1, jc_ = ((p)&1)<<7; \
    unsigned char* lb_ = (sbase); \
    const unsigned char* as_ = spk + (size_t)(m0 + srow32 - (d_<<6) + GUARD_ROWS)*J_DIM + jc_ + lcol; \
    gl16(as_,                     lb_         + wv1k); \
    gl16(as_ + (size_t)32*J_DIM,  lb_ + 4096  + wv1k); \
    gl16(as_ + (size_t)64*J_DIM,  lb_ + 8192  + wv1k); \
    gl16(as_ + (size_t)96*J_DIM,  lb_ + 12288 + wv1k); \
    const size_t bo_ = (size_t)(d_*H_DIM + n0 + srow32)*J_DIM + jc_ + lcol; \
    gl16(k0 + bo_,                    lb_ + 16384        + wv1k); \
    gl16(k0 + bo_ + (size_t)32*J_DIM, lb_ + 16384 + 4096 + wv1k); \
    gl16(k1 + bo_,                    lb_ + 24576        + wv1k); \
    gl16(k1 + bo_ + (size_t)32*J_DIM, lb_ + 24576 + 4096 + wv1k); \
    gl16(k2 + bo_,                    lb_ + 32768        + wv1k); \
    gl16(k2 + bo_ + (size_t)32*J_DIM, lb_ + 32768 + 4096 + wv1k); \
  }while(0)

  // prologue: stage period 0 into set 0
  STAGE(&lds[0][0], 0);

  for(int p=0; p<NPER; ++p){
    asm volatile("s_waitcnt vmcnt(0)" ::: "memory");  // own stage of set p&1 done
    __builtin_amdgcn_s_barrier();                     // => all waves' stages done
    __builtin_amdgcn_sched_barrier(0);
    if(p+1 < NPER) STAGE(&lds[(p+1)&1][0], p+1);      // issue early: full-period cover
    const unsigned char* S = &lds[p&1][0];
#pragma unroll
    for(int s=0;s<2;s++){
#pragma unroll
      for(int kk=0;kk<2;kk++){
        const int rs = ((((s<<2) + (kk<<1) + hlf) ^ l7) << 4);  // swizzled 16B slot
        i32x4 af0 = *(const i32x4*)(S + (wm0 +      l31)*128 + rs);
        i32x4 af1 = *(const i32x4*)(S + (wm0 + 32 + l31)*128 + rs);
        const int ro = (wn0 + l31)*128 + rs;
        const i32x4 b0 = *(const i32x4*)(S + 16384 + ro);
        const i32x4 b1 = *(const i32x4*)(S + 24576 + ro);
        const i32x4 b2 = *(const i32x4*)(S + 32768 + ro);
        __builtin_amdgcn_s_setprio(1);
        acc0[0] = __builtin_amdgcn_mfma_i32_32x32x32_i8(af0, b0, acc0[0], 0,0,0);
        acc1[0] = __builtin_amdgcn_mfma_i32_32x32x32_i8(af0, b1, acc1[0], 0,0,0);
        acc2[0] = __builtin_amdgcn_mfma_i32_32x32x32_i8(af0, b2, acc2[0], 0,0,0);
        acc0[1] = __builtin_amdgcn_mfma_i32_32x32x32_i8(af1, b0, acc0[1], 0,0,0);
        acc1[1] = __builtin_amdgcn_mfma_i32_32x32x32_i8(af1, b1, acc1[1], 0,0,0);
        acc2[1] = __builtin_amdgcn_mfma_i32_32x32x32_i8(af1, b2, acc2[1], 0,0,0);
        __builtin_amdgcn_s_setprio(0);
      }
    }
  }

  // epilogue: 32x32 C/D map [m74/m101]: col=lane&31,
  // row=(reg&3)+8*(reg>>2)+4*(lane>>5). Exact int64 digit recombine;
  // y-write; exact integer BN accumulation (order-independent).
  const int c0 = n0 + wn0 + l31;
  const double fs = (double)fsc[c0];
  long long s1 = 0; unsigned long long shi = 0, slo = 0;
#pragma unroll
  for(int mt=0;mt<2;mt++){
#pragma unroll
    for(int r=0;r<16;r++){
      const int row = (r&3) + ((r>>2)<<3) + (hlf<<2);
      const long long cmb = ((long long)acc2[mt][r] << 16)
                          + ((long long)acc1[mt][r] << 8)
                          +  (long long)acc0[mt][r];
      y[(size_t)(m0 + wm0 + mt*32 + row)*H_DIM + c0] = (float)((double)cmb * fs);
      s1 += cmb;
      const __int128 sq = (__int128)cmb * cmb;       // >= 0, < 2^70
      slo += (unsigned long long)(unsigned int)sq;   // low 32 bits
      shi += (unsigned long long)(sq >> 32);         // high bits
    }
  }
  s1  += __shfl_xor(s1, 32);
  shi += __shfl_xor(shi, 32);
  slo += __shfl_xor(slo, 32);
  if(lane < 32){
    atomicAdd((unsigned long long*)&part[c0],       (unsigned long long)s1);
    atomicAdd((unsigned long long*)&part[256 + c0], shi);
    atomicAdd((unsigned long long*)&part[512 + c0], slo);
  }
#undef STAGE
}

// ---------------------------------------------------------------------------
// 3) BN finalize from exact integer sums; re-zeros part for the next layer.
//    sum(y) = fs*s1 ; sum(y^2) = fs^2*(shi*2^32+slo) -- fs is a power of 2.
// ---------------------------------------------------------------------------
__global__ void bn_final_k(long long* __restrict__ part, const float* __restrict__ fsc,
                           float* __restrict__ sc, float* __restrict__ sh,
                           const float* __restrict__ gamma_, const float* __restrict__ bb_,
                           int layer){
  const int o = threadIdx.x;
  const long long s1           = part[o];
  const unsigned long long shi = (unsigned long long)part[256 + o];
  const unsigned long long slo = (unsigned long long)part[512 + o];
  part[o] = 0; part[256 + o] = 0; part[512 + o] = 0;   // ready for next layer
  const double fs  = (double)fsc[o];
  const double sy  = (double)s1 * fs;
  const double sy2 = ((double)shi * 4294967296.0 + (double)slo) * fs * fs;
  const double inv_n = 1.0 / (double)M_DIM;
  const double m   = sy * inv_n;
  const double var = sy2 * inv_n - m*m;      // biased, like jnp.var
  const double rs  = 1.0 / sqrt(var + (double)1e-5f);
  const float g  = gamma_[layer*H_DIM + o];
  const float bv = bb_[layer*H_DIM + o];
  const float scale = (float)((double)g * rs);
  sc[o] = scale;
  sh[o] = (float)((double)bv - m*(double)scale);
}

// ---------------------------------------------------------------------------
// 4) LIF soft-reset scan. One thread per (b,h), 16-deep prefetch.
//    TOUT=u8 inter-layer spikes, f32 final output (in-place on d_out).
//    NOTE: no __restrict__ on yin/sout — they alias for the final layer.
// ---------------------------------------------------------------------------
template<typename TOUT>
__global__ void lif_k(const float* yin, TOUT* sout,
                      const float* __restrict__ sc_, const float* __restrict__ sh_,
                      const float* __restrict__ beta_, const float* __restrict__ U0_,
                      int layer){
  const int idx = blockIdx.x*64 + threadIdx.x;   // 0..16383 = b*256+h
  const int h = idx & (H_DIM-1);
  const float scale = sc_[h];
  const float shift = sh_[h];
  const float beta  = beta_[layer*H_DIM + h];
  const float ombeta = 1.0f - beta;
  float U = U0_[layer*NBH + idx];
  float S = 0.f;
  float cur[16];
#pragma unroll
  for(int i=0;i<16;i++) cur[i] = yin[(size_t)i*NBH + idx];
  for(int t=0;t<T_DIM;t+=16){
    float nx[16];
#pragma unroll
    for(int i=0;i<16;i++){
      const int tt = t + 16 + i;
      nx[i] = (tt < T_DIM) ? yin[(size_t)tt*NBH + idx] : 0.f;
    }
#pragma unroll
    for(int i=0;i<16;i++){
      const float yv = fmaf(cur[i], scale, shift);
      U = beta*(U - S) + ombeta*yv;
      S = (U > 1.0f) ? 1.f : 0.f;              // (U - THETA) > 0
      sout[(size_t)(t+i)*NBH + idx] = (TOUT)S;
    }
#pragma unroll
    for(int i=0;i<16;i++) cur[i] = nx[i];
  }
}

// ---------------------------------------------------------------------------
// Launch. ws layout (13.7 MB):
//   spk  [0,          8,781,824)    guard(393216 zeros) + 32768*256 u8 spikes
//   k0   [8,781,824, 10,420,224)    25*256*256 i8 digit 0 (2^0)
//   k1   [10,420,224,12,058,624)    25*256*256 i8 digit 1 (2^8)
//   k2   [12,058,624,13,697,024)    25*256*256 i8 digit 2 (2^16)
//   fsc  [13,697,024,+1024)         256 f32 per-column scale
//   part [13,698,048,+8192)         3*256 i64 BN integer sums (+pad), zeroed
//   sc   [13,706,240,+1024) f32 ; sh [13,707,264,+1024) f32
// Conv y always lands in d_out (fully rewritten each layer before any read).
// ---------------------------------------------------------------------------
extern "C" void kernel_launch(void* const* d_in, const int* in_sizes, int n_in,
                              void* d_out, int out_size, void* d_ws, size_t ws_size,
                              hipStream_t stream){
  const float* x    = (const float*)d_in[0];
  const float* W    = (const float*)d_in[1];
  const float* P    = (const float*)d_in[2];
  const float* beta = (const float*)d_in[3];
  const float* gam  = (const float*)d_in[4];
  const float* bb   = (const float*)d_in[5];
  const float* U0   = (const float*)d_in[6];
  float* out = (float*)d_out;

  char* ws = (char*)d_ws;
  unsigned char* spk  = (unsigned char*)ws;                 // guarded base
  unsigned char* spkd = spk + GUARD_BYTES;                  // data region
  signed char*   k0   = (signed char*)(ws + 8781824);
  signed char*   k1   = (signed char*)(ws + 10420224);
  signed char*   k2   = (signed char*)(ws + 12058624);
  float*         fsc  = (float*)(ws + 13697024);
  long long*     part = (long long*)(ws + 13698048);
  float*         sc   = (float*)(ws + 13706240);
  float*         sh   = sc + 256;

  zero_guard_k<<<dim3(98), dim3(256), 0, stream>>>(spk, (unsigned char*)part);
  cast_u8_k<<<dim3((M_DIM*J_DIM)/1024), dim3(256), 0, stream>>>(x, spkd);

  for(int l=0;l<NL;l++){
    build_kern_k<<<dim3(H_DIM), dim3(J_DIM), 0, stream>>>(W, P, k0, k1, k2, fsc, l);
    conv_mfma_k<<<dim3((M_DIM/MB)*(H_DIM/NB)), dim3(256), 0, stream>>>(spk, k0, k1, k2, fsc, out, part);
    bn_final_k<<<dim3(1), dim3(H_DIM), 0, stream>>>(part, fsc, sc, sh, gam, bb, l);
    if(l < NL-1) lif_k<unsigned char><<<dim3(NBH/64), dim3(64), 0, stream>>>(out, spkd, sc, sh, beta, U0, l);
    else         lif_k<float>        <<<dim3(NBH/64), dim3(64), 0, stream>>>(out, out, sc, sh, beta, U0, l);
  }
}

// Round 20
// 478.653 us; speedup vs baseline: 1.6653x; 1.1586x over previous
//
#include <hip/hip_runtime.h>
#include <math.h>

// Model dims (fixed by the reference)
#define T_DIM 512
#define B_DIM 64
#define J_DIM 256
#define H_DIM 256
#define K_TAP 25
#define NL    3
#define M_DIM (T_DIM*B_DIM)   // 32768 rows = (t,b)
#define NBH   (B_DIM*H_DIM)   // 16384
#define GUARD_ROWS 1536                  // 64*24 zero rows before row 0
#define GUARD_BYTES (GUARD_ROWS*J_DIM)   // 393216

// conv GEMM tiling: 128(M) x 64(N) block, 4 waves (2x2), wave tile 64x32.
// PERIOD = 128 K-elems (2 MFMA sub-steps of 64). 50 periods.
#define MB 128
#define NB 64
#define NPER 50
#define SETB 40960   // per LDS set: A[128][128] @0 | B0 @16384 | B1 @24576 | B2 @32768

typedef __attribute__((ext_vector_type(4))) int   i32x4;

__device__ __forceinline__ void gl16(const void* g, void* l){ // async global->LDS, 16B/lane
  __builtin_amdgcn_global_load_lds((const __attribute__((address_space(1))) unsigned int*)g,
                                   (__attribute__((address_space(3))) unsigned int*)l, 16, 0, 0);
}

// ---------------------------------------------------------------------------
// 0a) zero guard region + BN integer-accumulator region (ws is poisoned)
// ---------------------------------------------------------------------------
__global__ void zero_guard_k(unsigned char* __restrict__ g, unsigned char* __restrict__ p){
  const int bid = blockIdx.x;
  if(bid < 96) *(uint4*)(g + (size_t)(bid*256 + threadIdx.x)*16) = (uint4){0,0,0,0};
  else         *(uint4*)(p + (size_t)((bid-96)*256 + threadIdx.x)*16) = (uint4){0,0,0,0};
}

// 0b) cast f32 binary input -> u8 spikes
__global__ void cast_u8_k(const float* __restrict__ x, unsigned char* __restrict__ s){
  const int i = blockIdx.x*256 + threadIdx.x;       // one float4 per thread
  const float4 v = *(const float4*)(x + (size_t)i*4);
  uchar4 o; o.x=(unsigned char)v.x; o.y=(unsigned char)v.y;
  o.z=(unsigned char)v.z; o.w=(unsigned char)v.w;
  *(uchar4*)(s + (size_t)i*4) = o;
}

// ---------------------------------------------------------------------------
// 1) DCLS gaussian kernel -> 23-bit fixed point, 3 signed-i8 digit planes.
//    kd[d][o][j] = W[o,j]*gnorm[o,j,k=24-d].  Per-column power-of-2 scale s_o;
//    q = rint(kd/s_o * 2^22); q = b2*2^16 + b1*2^8 + b0 exactly.
//    fsc[o] = s_o * 2^-22 (exact power of 2).
// ---------------------------------------------------------------------------
__global__ void build_kern_k(const float* __restrict__ W, const float* __restrict__ P,
                             signed char* __restrict__ k0, signed char* __restrict__ k1,
                             signed char* __restrict__ k2, float* __restrict__ fsc, int layer){
  __shared__ float red[256];
  const int o = blockIdx.x, j = threadIdx.x;
  const float w = W[(layer*H_DIM + o)*J_DIM + j];
  const float p = P[(layer*H_DIM + o)*J_DIM + j];
  const float c = p + 12.0f;              // P + K//2
  const float sg = 0.77f;                 // |0.5| + 0.27
  float v[K_TAP]; float ssum = 0.f;
#pragma unroll
  for(int k=0;k<K_TAP;k++){ float z = ((float)k - c)/sg; v[k] = expf(-0.5f*z*z); ssum += v[k]; }
  const float inv = 1.0f/(ssum + 1e-7f);
  float mv = 0.f;
#pragma unroll
  for(int k=0;k<K_TAP;k++){ v[k] = w * (v[k]*inv); mv = fmaxf(mv, fabsf(v[k])); }
  red[j] = mv; __syncthreads();
  for(int st=128; st; st>>=1){ if(j<st) red[j] = fmaxf(red[j], red[j+st]); __syncthreads(); }
  int e; frexpf(red[0], &e);              // maxv = f*2^e, f in [0.5,1)
  const float invq = ldexpf(1.f, 22 - e); // 2^22 / s_o
#pragma unroll
  for(int k=0;k<K_TAP;k++){
    const int d = (K_TAP-1)-k;
    int q = (int)lrintf(v[k]*invq);
    const int b0 = (int)(signed char)(q & 0xFF); q = (q - b0) >> 8;
    const int b1 = (int)(signed char)(q & 0xFF); q = (q - b1) >> 8;
    const size_t idx = (size_t)(d*H_DIM + o)*J_DIM + j;
    k0[idx] = (signed char)b0; k1[idx] = (signed char)b1; k2[idx] = (signed char)q;
  }
  if(j==0) fsc[o] = ldexpf(1.f, e - 22);
}

// ---------------------------------------------------------------------------
// 2) Delayed causal conv as EXACT i8 MFMA GEMM (3 digit planes, i32 acc).
//    128x64 block, 4 waves 2x2, wave tile 64x32, mfma_i32_16x16x64_i8.
//    PERIOD = 128 K-elems (2 sub-steps): ONE {vmcnt(0); s_barrier} per
//    period, 2-set double-buffered 40KB LDS sets (80KB -> 2 blocks/CU).
//    STAGE of the other set issues IMMEDIATELY post-barrier -> a full
//    ~period of latency cover; the out-of-phase second block on the CU
//    hides the drain tail.
//    Race proof (r14 pattern): set s=(p+1)&1 staged during period p was
//    last read in period p-1; those ds_reads are lgkm-retired before each
//    wave's MFMAs, which precede barrier(p); stage writes issue only after
//    barrier(p). Reads of the current set follow each wave's own vmcnt(0)
//    drain + barrier -> all waves' writes visible.
//    128B rows -> 8-slot swizzle: phys16Bslot = logical ^ (row&7); gl16
//    stays linear with SOURCE col pre-permuted (rule 21 both-sides).
//    16x16 fragment reads = 2 lanes/slot per 16-lane group = conflict-free
//    (r19 lesson: 32x32 fragments force 4-way conflicts at 128B rows).
//    XCD n0-major (T1); fused exact-integer BN epilogue.
// ---------------------------------------------------------------------------
__global__ __launch_bounds__(256,2) void conv_mfma_k(const unsigned char* __restrict__ spk,
    const signed char* __restrict__ k0, const signed char* __restrict__ k1,
    const signed char* __restrict__ k2, const float* __restrict__ fsc,
    float* __restrict__ y, long long* __restrict__ part){
  __shared__ unsigned char lds[2][SETB];
  const int tid = threadIdx.x, lane = tid & 63, wave = tid >> 6;
  // XCD-aware n0-major decode: xcd = bid%8 owns 128 consecutive q's
  const int bid = blockIdx.x;                      // 0..1023
  const int q   = (bid & 7)*128 + (bid >> 3);
  const int m0  = (q & 255) * MB;
  const int n0  = (q >> 8) * NB;
  const int wm0 = (wave >> 1) << 6;   // 0 / 64
  const int wn0 = (wave & 1) << 5;    // 0 / 32

  // staging map: thread t -> row 32i + (t>>3), phys 16B slot t&7;
  // source col pre-permuted: lcol = ((t&7) ^ ((t>>3)&7)) * 16
  const int srow32 = tid >> 3;                       // 0..31
  const int lcol   = (((tid & 7) ^ (srow32 & 7)) << 4);
  const int wv1k   = wave * 1024;
  const int l15 = lane & 15, l7 = lane & 7, lg = lane >> 4;

  i32x4 acc0[4][2], acc1[4][2], acc2[4][2];
#pragma unroll
  for(int m=0;m<4;m++)
#pragma unroll
    for(int n=0;n<2;n++){
      acc0[m][n] = (i32x4){0,0,0,0};
      acc1[m][n] = (i32x4){0,0,0,0};
      acc2[m][n] = (i32x4){0,0,0,0};
    }

#define STAGE(sbase,p) do{ \
    const int d_ = (p)>>1, jc_ = ((p)&1)<<7; \
    unsigned char* lb_ = (sbase); \
    const unsigned char* as_ = spk + (size_t)(m0 + srow32 - (d_<<6) + GUARD_ROWS)*J_DIM + jc_ + lcol; \
    gl16(as_,                     lb_         + wv1k); \
    gl16(as_ + (size_t)32*J_DIM,  lb_ + 4096  + wv1k); \
    gl16(as_ + (size_t)64*J_DIM,  lb_ + 8192  + wv1k); \
    gl16(as_ + (size_t)96*J_DIM,  lb_ + 12288 + wv1k); \
    const size_t bo_ = (size_t)(d_*H_DIM + n0 + srow32)*J_DIM + jc_ + lcol; \
    gl16(k0 + bo_,                    lb_ + 16384        + wv1k); \
    gl16(k0 + bo_ + (size_t)32*J_DIM, lb_ + 16384 + 4096 + wv1k); \
    gl16(k1 + bo_,                    lb_ + 24576        + wv1k); \
    gl16(k1 + bo_ + (size_t)32*J_DIM, lb_ + 24576 + 4096 + wv1k); \
    gl16(k2 + bo_,                    lb_ + 32768        + wv1k); \
    gl16(k2 + bo_ + (size_t)32*J_DIM, lb_ + 32768 + 4096 + wv1k); \
  }while(0)

  // prologue: stage period 0 into set 0
  STAGE(&lds[0][0], 0);

  for(int p=0; p<NPER; ++p){
    asm volatile("s_waitcnt vmcnt(0)" ::: "memory");  // own stage of set p&1 done
    __builtin_amdgcn_s_barrier();                     // => all waves' stages done
    __builtin_amdgcn_sched_barrier(0);
    if(p+1 < NPER) STAGE(&lds[(p+1)&1][0], p+1);      // issue early: full-period cover
    const unsigned char* S = &lds[p&1][0];
#pragma unroll
    for(int s=0;s<2;s++){
      const int rs = (((lg + (s<<2)) ^ l7) << 4);     // swizzled 16B slot
      i32x4 af[4], b0f[2], b1f[2], b2f[2];
#pragma unroll
      for(int m=0;m<4;m++)
        af[m] = *(const i32x4*)(S + (wm0 + m*16 + l15)*128 + rs);
#pragma unroll
      for(int n=0;n<2;n++){
        const int ro = (wn0 + n*16 + l15)*128 + rs;
        b0f[n] = *(const i32x4*)(S + 16384 + ro);
        b1f[n] = *(const i32x4*)(S + 24576 + ro);
        b2f[n] = *(const i32x4*)(S + 32768 + ro);
      }
      __builtin_amdgcn_s_setprio(1);
#pragma unroll
      for(int m=0;m<4;m++)
#pragma unroll
        for(int n=0;n<2;n++){
          acc0[m][n] = __builtin_amdgcn_mfma_i32_16x16x64_i8(af[m], b0f[n], acc0[m][n], 0,0,0);
          acc1[m][n] = __builtin_amdgcn_mfma_i32_16x16x64_i8(af[m], b1f[n], acc1[m][n], 0,0,0);
          acc2[m][n] = __builtin_amdgcn_mfma_i32_16x16x64_i8(af[m], b2f[n], acc2[m][n], 0,0,0);
        }
      __builtin_amdgcn_s_setprio(0);
    }
  }

  // epilogue: C/D mapping col=lane&15, row=(lane>>4)*4+r [shape-determined].
  // Exact int64 digit recombine; y-write; exact integer BN accumulation.
  const int r0 = m0 + wm0 + ((lane>>4)<<2);
  const int c0 = n0 + wn0 + (lane&15);
  const double f0 = (double)fsc[c0];
  const double f1 = (double)fsc[c0+16];
#pragma unroll
  for(int n=0;n<2;n++){
    const double fs = n ? f1 : f0;
    long long s1 = 0; unsigned long long shi = 0, slo = 0;
#pragma unroll
    for(int m=0;m<4;m++)
#pragma unroll
      for(int r=0;r<4;r++){
        const long long cmb = ((long long)acc2[m][n][r] << 16)
                            + ((long long)acc1[m][n][r] << 8)
                            +  (long long)acc0[m][n][r];
        y[(size_t)(r0 + m*16 + r)*H_DIM + c0 + n*16] = (float)((double)cmb * fs);
        s1 += cmb;
        const __int128 sq = (__int128)cmb * cmb;       // >= 0, < 2^70
        slo += (unsigned long long)(unsigned int)sq;   // low 32 bits
        shi += (unsigned long long)(sq >> 32);         // high bits (< 2^38)
      }
    s1  += __shfl_xor(s1, 16);  s1  += __shfl_xor(s1, 32);
    shi += __shfl_xor(shi, 16); shi += __shfl_xor(shi, 32);
    slo += __shfl_xor(slo, 16); slo += __shfl_xor(slo, 32);
    if(lane < 16){
      const int c = c0 + n*16;
      atomicAdd((unsigned long long*)&part[c],       (unsigned long long)s1);
      atomicAdd((unsigned long long*)&part[256 + c], shi);
      atomicAdd((unsigned long long*)&part[512 + c], slo);
    }
  }
#undef STAGE
}

// ---------------------------------------------------------------------------
// 3) BN finalize from exact integer sums; re-zeros part for the next layer.
//    sum(y) = fs*s1 ; sum(y^2) = fs^2*(shi*2^32+slo) -- fs is a power of 2.
// ---------------------------------------------------------------------------
__global__ void bn_final_k(long long* __restrict__ part, const float* __restrict__ fsc,
                           float* __restrict__ sc, float* __restrict__ sh,
                           const float* __restrict__ gamma_, const float* __restrict__ bb_,
                           int layer){
  const int o = threadIdx.x;
  const long long s1           = part[o];
  const unsigned long long shi = (unsigned long long)part[256 + o];
  const unsigned long long slo = (unsigned long long)part[512 + o];
  part[o] = 0; part[256 + o] = 0; part[512 + o] = 0;   // ready for next layer
  const double fs  = (double)fsc[o];
  const double sy  = (double)s1 * fs;
  const double sy2 = ((double)shi * 4294967296.0 + (double)slo) * fs * fs;
  const double inv_n = 1.0 / (double)M_DIM;
  const double m   = sy * inv_n;
  const double var = sy2 * inv_n - m*m;      // biased, like jnp.var
  const double rs  = 1.0 / sqrt(var + (double)1e-5f);
  const float g  = gamma_[layer*H_DIM + o];
  const float bv = bb_[layer*H_DIM + o];
  const float scale = (float)((double)g * rs);
  sc[o] = scale;
  sh[o] = (float)((double)bv - m*(double)scale);
}

// ---------------------------------------------------------------------------
// 4) LIF soft-reset scan. One thread per (b,h), 16-deep prefetch.
//    TOUT=u8 inter-layer spikes, f32 final output (in-place on d_out).
//    NOTE: no __restrict__ on yin/sout — they alias for the final layer.
// ---------------------------------------------------------------------------
template<typename TOUT>
__global__ void lif_k(const float* yin, TOUT* sout,
                      const float* __restrict__ sc_, const float* __restrict__ sh_,
                      const float* __restrict__ beta_, const float* __restrict__ U0_,
                      int layer){
  const int idx = blockIdx.x*64 + threadIdx.x;   // 0..16383 = b*256+h
  const int h = idx & (H_DIM-1);
  const float scale = sc_[h];
  const float shift = sh_[h];
  const float beta  = beta_[layer*H_DIM + h];
  const float ombeta = 1.0f - beta;
  float U = U0_[layer*NBH + idx];
  float S = 0.f;
  float cur[16];
#pragma unroll
  for(int i=0;i<16;i++) cur[i] = yin[(size_t)i*NBH + idx];
  for(int t=0;t<T_DIM;t+=16){
    float nx[16];
#pragma unroll
    for(int i=0;i<16;i++){
      const int tt = t + 16 + i;
      nx[i] = (tt < T_DIM) ? yin[(size_t)tt*NBH + idx] : 0.f;
    }
#pragma unroll
    for(int i=0;i<16;i++){
      const float yv = fmaf(cur[i], scale, shift);
      U = beta*(U - S) + ombeta*yv;
      S = (U > 1.0f) ? 1.f : 0.f;              // (U - THETA) > 0
      sout[(size_t)(t+i)*NBH + idx] = (TOUT)S;
    }
#pragma unroll
    for(int i=0;i<16;i++) cur[i] = nx[i];
  }
}

// ---------------------------------------------------------------------------
// Launch. ws layout (13.7 MB):
//   spk  [0,          8,781,824)    guard(393216 zeros) + 32768*256 u8 spikes
//   k0   [8,781,824, 10,420,224)    25*256*256 i8 digit 0 (2^0)
//   k1   [10,420,224,12,058,624)    25*256*256 i8 digit 1 (2^8)
//   k2   [12,058,624,13,697,024)    25*256*256 i8 digit 2 (2^16)
//   fsc  [13,697,024,+1024)         256 f32 per-column scale
//   part [13,698,048,+8192)         3*256 i64 BN integer sums (+pad), zeroed
//   sc   [13,706,240,+1024) f32 ; sh [13,707,264,+1024) f32
// Conv y always lands in d_out (fully rewritten each layer before any read).
// ---------------------------------------------------------------------------
extern "C" void kernel_launch(void* const* d_in, const int* in_sizes, int n_in,
                              void* d_out, int out_size, void* d_ws, size_t ws_size,
                              hipStream_t stream){
  const float* x    = (const float*)d_in[0];
  const float* W    = (const float*)d_in[1];
  const float* P    = (const float*)d_in[2];
  const float* beta = (const float*)d_in[3];
  const float* gam  = (const float*)d_in[4];
  const float* bb   = (const float*)d_in[5];
  const float* U0   = (const float*)d_in[6];
  float* out = (float*)d_out;

  char* ws = (char*)d_ws;
  unsigned char* spk  = (unsigned char*)ws;                 // guarded base
  unsigned char* spkd = spk + GUARD_BYTES;                  // data region
  signed char*   k0   = (signed char*)(ws + 8781824);
  signed char*   k1   = (signed char*)(ws + 10420224);
  signed char*   k2   = (signed char*)(ws + 12058624);
  float*         fsc  = (float*)(ws + 13697024);
  long long*     part = (long long*)(ws + 13698048);
  float*         sc   = (float*)(ws + 13706240);
  float*         sh   = sc + 256;

  zero_guard_k<<<dim3(98), dim3(256), 0, stream>>>(spk, (unsigned char*)part);
  cast_u8_k<<<dim3((M_DIM*J_DIM)/1024), dim3(256), 0, stream>>>(x, spkd);

  for(int l=0;l<NL;l++){
    build_kern_k<<<dim3(H_DIM), dim3(J_DIM), 0, stream>>>(W, P, k0, k1, k2, fsc, l);
    conv_mfma_k<<<dim3((M_DIM/MB)*(H_DIM/NB)), dim3(256), 0, stream>>>(spk, k0, k1, k2, fsc, out, part);
    bn_final_k<<<dim3(1), dim3(H_DIM), 0, stream>>>(part, fsc, sc, sh, gam, bb, l);
    if(l < NL-1) lif_k<unsigned char><<<dim3(NBH/64), dim3(64), 0, stream>>>(out, spkd, sc, sh, beta, U0, l);
    else         lif_k<float>        <<<dim3(NBH/64), dim3(64), 0, stream>>>(out, out, sc, sh, beta, U0, l);
  }
}